// Round 7
// baseline (206.355 us; speedup 1.0000x reference)
//
#include <hip/hip_runtime.h>
#include <hip/hip_bf16.h>

typedef __bf16 bf16x8 __attribute__((ext_vector_type(8)));
typedef __bf16 bf16x4 __attribute__((ext_vector_type(4)));
typedef __bf16 bf16x2 __attribute__((ext_vector_type(2)));
typedef float fx4 __attribute__((ext_vector_type(4)));
typedef float fx16 __attribute__((ext_vector_type(16)));

#define AS1 __attribute__((address_space(1)))
#define AS3 __attribute__((address_space(3)))

// ---------------------------------------------------------------- prep: cast x -> bf16  +  all 4 weight transposes
__global__ __launch_bounds__(256) void prep(const float4* __restrict__ X, __bf16* __restrict__ Xb,
                                            const float* __restrict__ wq, const float* __restrict__ wk,
                                            const float* __restrict__ wv, const float* __restrict__ wo,
                                            __bf16* __restrict__ WqkvT, __bf16* __restrict__ WoT) {
    const int bx = blockIdx.x;
    if (bx < 4096) {
        const int i = bx * 256 + threadIdx.x;
        const float4 v = X[i];
        bf16x4 o = { (__bf16)v.x, (__bf16)v.y, (__bf16)v.z, (__bf16)v.w };
        *(bf16x4*)(Xb + (size_t)i * 4) = o;
        return;
    }
    constexpr int K = 2048;
    __shared__ float t[64][33];
    const int tt = bx - 4096;
    const float* W; __bf16* Wt; int N, loc;
    if (tt < 2048)      { W = wq; Wt = WqkvT;                       N = 2048; loc = tt; }
    else if (tt < 2560) { W = wk; Wt = WqkvT + (size_t)2048 * 2048; N = 512;  loc = tt - 2048; }
    else if (tt < 3072) { W = wv; Wt = WqkvT + (size_t)2560 * 2048; N = 512;  loc = tt - 2560; }
    else                { W = wo; Wt = WoT;                         N = 2048; loc = tt - 3072; }
    const int k0 = (loc & 31) * 64, n0 = (loc >> 5) * 32;
    const int tx = threadIdx.x & 31, ty = threadIdx.x >> 5;
#pragma unroll
    for (int i = 0; i < 8; ++i)
        t[ty + i * 8][tx] = W[(size_t)(k0 + ty + i * 8) * N + n0 + tx];
    __syncthreads();
#pragma unroll
    for (int i = 0; i < 4; ++i) {
        const int nn = ty + i * 8;
        bf16x2 o = { (__bf16)t[tx * 2][nn], (__bf16)t[tx * 2 + 1][nn] };
        *(bf16x2*)&Wt[(size_t)(n0 + nn) * K + k0 + tx * 2] = o;
    }
}

// ================================================= shared GEMM pieces: BM=128 BN=128 BK=32,
// 4 waves (64x64 wave-tile), 3-buffer depth-2 counted-vmcnt ring, XOR-swizzled LDS.
#define GL(p, d) __builtin_amdgcn_global_load_lds((const AS1 void*)(p), (AS3 void*)(d), 16, 0, 0)
#define WBAR(N)  asm volatile("s_waitcnt vmcnt(" #N ") lgkmcnt(0)" ::: "memory");             \
                 __builtin_amdgcn_s_barrier();                                                \
                 __builtin_amdgcn_sched_barrier(0)

#define GEMM_PRE(Aptr, Btptr, KBEG)                                                          \
    constexpr int K = 2048;                                                                  \
    __shared__ __align__(16) __bf16 sm[3][8192];    /* 48 KB */                              \
    const int tid = threadIdx.x;                                                             \
    const int wave = tid >> 6, lane = tid & 63;                                              \
    const int quad = lane >> 4, l16 = lane & 15;                                             \
    const int wm = (wave >> 1) * 64, wn = (wave & 1) * 64;                                   \
    fx4 acc[4][4] = {};                                                                      \
    const int r4 = lane >> 2;                                                                \
    const int c8s = ((lane & 3) ^ ((r4 >> 1) & 3)) * 8;                                      \
    const __bf16* csrc[4]; int cdst[4];                                                      \
    _Pragma("unroll")                                                                        \
    for (int it = 0; it < 4; ++it) {                                                         \
        const int idx = wave * 4 + it;                                                       \
        if (idx < 8) { csrc[it] = (Aptr) + (size_t)(m0 + idx * 16 + r4) * K + c8s + (KBEG);  \
                       cdst[it] = idx * 512 + lane * 8; }                                    \
        else         { csrc[it] = (Btptr) + (size_t)(n0 + (idx - 8) * 16 + r4) * K + c8s + (KBEG); \
                       cdst[it] = 4096 + (idx - 8) * 512 + lane * 8; }                       \
    }                                                                                        \
    const int colr = (quad ^ ((l16 >> 1) & 3)) * 8;                                          \
    const int arow = (wm + l16) * 32 + colr;                                                 \
    const int brow = 4096 + (wn + l16) * 32 + colr;                                          \
    auto compute = [&](const __bf16* cb) {                                                   \
        bf16x8 af[4], bfr[4];                                                                \
        _Pragma("unroll") for (int i = 0; i < 4; ++i) af[i]  = *(const bf16x8*)&cb[arow + i * 512]; \
        _Pragma("unroll") for (int j = 0; j < 4; ++j) bfr[j] = *(const bf16x8*)&cb[brow + j * 512]; \
        __builtin_amdgcn_s_setprio(1);                                                       \
        _Pragma("unroll") for (int i = 0; i < 4; ++i)                                        \
            _Pragma("unroll") for (int j = 0; j < 4; ++j)                                    \
                acc[i][j] = __builtin_amdgcn_mfma_f32_16x16x32_bf16(af[i], bfr[j], acc[i][j], 0, 0, 0); \
        __builtin_amdgcn_s_setprio(0);                                                       \
    };                                                                                       \
    _Pragma("unroll")                                                                        \
    for (int pt = 0; pt < 2; ++pt)                                                           \
        _Pragma("unroll")                                                                    \
        for (int it = 0; it < 4; ++it)                                                       \
            GL(csrc[it] + pt * 32, &sm[pt][cdst[it]]);

#define GEMM_LOOP_64                                                                         \
    _Pragma("unroll 1")                                                                      \
    for (int tq = 0; tq < 20; ++tq) {                                                        \
        _Pragma("unroll")                                                                    \
        for (int u = 0; u < 3; ++u) {                                                        \
            const int t = tq * 3 + u;                                                        \
            WBAR(4);                                                                         \
            const int kofs = (t + 2) * 32;                                                   \
            _Pragma("unroll")                                                                \
            for (int it = 0; it < 4; ++it)                                                   \
                GL(csrc[it] + kofs, &sm[(u + 2) % 3][cdst[it]]);                             \
            compute(sm[u]);                                                                  \
        }                                                                                    \
    }                                                                                        \
    { WBAR(4); _Pragma("unroll") for (int it = 0; it < 4; ++it)                              \
          GL(csrc[it] + 62 * 32, &sm[2][cdst[it]]); compute(sm[0]); }  /* t=60 */            \
    { WBAR(4); _Pragma("unroll") for (int it = 0; it < 4; ++it)                              \
          GL(csrc[it] + 63 * 32, &sm[0][cdst[it]]); compute(sm[1]); }  /* t=61 */            \
    { WBAR(4); compute(sm[2]); }                                       /* t=62 */            \
    { WBAR(0); compute(sm[0]); }                                       /* t=63 */

#define GEMM_LOOP_32                                                                         \
    _Pragma("unroll 1")                                                                      \
    for (int tq = 0; tq < 10; ++tq) {                                                        \
        _Pragma("unroll")                                                                    \
        for (int u = 0; u < 3; ++u) {                                                        \
            const int t = tq * 3 + u;                                                        \
            WBAR(4);                                                                         \
            const int kofs = (t + 2) * 32;                                                   \
            _Pragma("unroll")                                                                \
            for (int it = 0; it < 4; ++it)                                                   \
                GL(csrc[it] + kofs, &sm[(u + 2) % 3][cdst[it]]);                             \
            compute(sm[u]);                                                                  \
        }                                                                                    \
    }                                                                                        \
    { WBAR(4); compute(sm[0]); }                                       /* t=30 */            \
    { WBAR(0); compute(sm[1]); }                                       /* t=31 */

// ------------------------------------------------- QKV GEMM with fused RoPE/split epilogue
__global__ __launch_bounds__(256, 3) void gemm_qkv(const __bf16* __restrict__ A, const __bf16* __restrict__ Bt,
                                                   __bf16* __restrict__ Qr, __bf16* __restrict__ Kr,
                                                   __bf16* __restrict__ Vt) {
    // XCD-chunked swizzle, nwg = 384 = 8*48
    const int bid = blockIdx.x;
    const int swz = (bid & 7) * 48 + (bid >> 3);
    const int m0 = (swz & 15) * 128, n0 = (swz >> 4) * 128;

    GEMM_PRE(A, Bt, 0)
    GEMM_LOOP_64

    // epilogue: each wave's 64 cols (col64..col64+63) are exactly one head
    const int col64 = n0 + wn;
    if (col64 < 2560) {
        const bool isQ = col64 < 2048;
        const float scale = isQ ? 0.18033688011112042f : 1.0f;   // Q: 0.125*log2(e)
        __bf16* base = isQ ? (Qr + (size_t)(col64 >> 6) * 2048 * 64)
                           : (Kr + (size_t)((col64 - 2048) >> 6) * 2048 * 64);
#pragma unroll
        for (int jj = 0; jj < 2; ++jj) {
            const int dlo = jj * 16 + l16;
            const float inv = __builtin_amdgcn_exp2f(-(float)dlo * 0.41524101186092029f);
#pragma unroll
            for (int i = 0; i < 4; ++i)
#pragma unroll
                for (int r = 0; r < 4; ++r) {
                    const int s = m0 + wm + i * 16 + quad * 4 + r;
                    float sn, cs;
                    __sincosf((float)s * inv, &sn, &cs);
                    const float lo = acc[i][jj][r], hv = acc[i][jj + 2][r];
                    base[(size_t)s * 64 + dlo]      = (__bf16)((lo * cs - hv * sn) * scale);
                    base[(size_t)s * 64 + dlo + 32] = (__bf16)((hv * cs + lo * sn) * scale);
                }
        }
    } else {
        __bf16* vb = Vt + (size_t)((col64 - 2560) >> 6) * 64 * 2048;
#pragma unroll
        for (int i = 0; i < 4; ++i)
#pragma unroll
            for (int j = 0; j < 4; ++j) {
                const int d = j * 16 + l16;
                const int s0 = m0 + wm + i * 16 + quad * 4;
                bf16x4 p;
#pragma unroll
                for (int r = 0; r < 4; ++r) p[r] = (__bf16)acc[i][j][r];
                *(bf16x4*)&vb[(size_t)d * 2048 + s0] = p;
            }
    }
}

// ------------------------------------------------- out-projection GEMM, split-K=2 (512 blocks = 2/CU)
__global__ __launch_bounds__(256, 3) void gemm_out_sk(const __bf16* __restrict__ A, const __bf16* __restrict__ Bt,
                                                      float* __restrict__ C0, float* __restrict__ C1) {
    const int bid = blockIdx.x;              // 0..511
    const int kz = bid >> 8;
    const int b8 = bid & 255;
    const int swz = (b8 & 7) * 32 + (b8 >> 3);
    const int m0 = (swz & 15) * 128, n0 = (swz >> 4) * 128;
    const int kbeg = kz << 10;               // 0 or 1024
    float* C = kz ? C1 : C0;

    GEMM_PRE(A, Bt, kbeg)
    GEMM_LOOP_32

#pragma unroll
    for (int i = 0; i < 4; ++i)
#pragma unroll
        for (int j = 0; j < 4; ++j) {
            const int row = m0 + wm + i * 16 + quad * 4;
            const int col = n0 + wn + j * 16 + l16;
#pragma unroll
            for (int r = 0; r < 4; ++r)
                C[(size_t)(row + r) * 2048 + col] = acc[i][j][r];
        }
}

// ------------------------------------------------- out += partial (deterministic split-K reduce)
__global__ __launch_bounds__(256) void reduce_add(float4* __restrict__ out, const float4* __restrict__ p) {
    const int i = blockIdx.x * 256 + threadIdx.x;
    float4 a = out[i];
    const float4 b = p[i];
    a.x += b.x; a.y += b.y; a.z += b.z; a.w += b.w;
    out[i] = a;
}

// ------------------------------------------------- flash attention: 4-wave blocks, 64 q-rows PER WAVE
// (2 Q sub-blocks share each K/V LDS read -> LDS reads per MFMA halved vs r6), split-K 2 groups
// of 2 waves, K+V LDS dbuf (73728 B), grid (16 qt, 32 h) = 512 blocks = 2/CU, raw lgkm barriers.
__global__ __launch_bounds__(256, 2) void flash_attn(const __bf16* __restrict__ Qr, const __bf16* __restrict__ Kr,
                                                     const __bf16* __restrict__ Vt, __bf16* __restrict__ O) {
    constexpr int S = 2048;
    __shared__ __align__(16) __bf16 smem[2][4 * 4608];   // [buf][grp: K 4608 | V 4608] = 73728 B
    const int qt = blockIdx.x, h = blockIdx.y, kvh = h >> 2;
    const int tid = threadIdx.x, wave = tid >> 6, lane = tid & 63;
    const int grp = wave >> 1, w2 = wave & 1;
    const int l32 = lane & 31, hi = lane >> 5;
    const int goff = grp * 9216;

    const int qrowA = qt * 128 + w2 * 64 + l32;          // sub-block A rows; B = +32
    const __bf16* qptr = Qr + ((size_t)h * S + qrowA) * 64;
    bf16x8 qfA[4], qfB[4];
#pragma unroll
    for (int kc = 0; kc < 4; ++kc) {
        qfA[kc] = *(const bf16x8*)(qptr + kc * 16 + hi * 8);
        qfB[kc] = *(const bf16x8*)(qptr + 32 * 64 + kc * 16 + hi * 8);
    }

    const __bf16* Kbase = Kr + (size_t)kvh * S * 64;
    const __bf16* Vbase = Vt + (size_t)kvh * 64 * S;

    // staging: 128 threads per group; each thread covers rows {krow, krow+32} x 16 cols
    const int gi = tid & 127;
    const int krow = gi >> 2;                 // 0..31
    const int kc16 = (gi & 3) * 16;           // 0,16,32,48

    bf16x8 kr0, kr1, kr2, kr3, vr0, vr1, vr2, vr3;

#define LOADREGS(kt) do {                                                             \
        const size_t co = (size_t)(kt) * 64;                                          \
        kr0 = *(const bf16x8*)(Kbase + (co + krow) * 64 + kc16);                      \
        kr1 = *(const bf16x8*)(Kbase + (co + krow) * 64 + kc16 + 8);                  \
        kr2 = *(const bf16x8*)(Kbase + (co + 32 + krow) * 64 + kc16);                 \
        kr3 = *(const bf16x8*)(Kbase + (co + 32 + krow) * 64 + kc16 + 8);             \
        vr0 = *(const bf16x8*)(Vbase + (size_t)krow * S + co + kc16);                 \
        vr1 = *(const bf16x8*)(Vbase + (size_t)krow * S + co + kc16 + 8);             \
        vr2 = *(const bf16x8*)(Vbase + (size_t)(32 + krow) * S + co + kc16);          \
        vr3 = *(const bf16x8*)(Vbase + (size_t)(32 + krow) * S + co + kc16 + 8);      \
    } while (0)

    // V perm: within each 16-col group, nibbles {0-3}->{0-3}, {4-7}->{8-11}, {8-11}->{4-7}, {12-15}->{12-15}
#define STAGE(buf) do {                                                               \
        __bf16* nK = &smem[buf][goff];                                                \
        __bf16* nV = nK + 4608;                                                       \
        *(bf16x8*)&nK[krow * 72 + kc16]            = kr0;                             \
        *(bf16x8*)&nK[krow * 72 + kc16 + 8]        = kr1;                             \
        *(bf16x8*)&nK[(32 + krow) * 72 + kc16]     = kr2;                             \
        *(bf16x8*)&nK[(32 + krow) * 72 + kc16 + 8] = kr3;                             \
        bf16x4 a0_ = { vr0[0],vr0[1],vr0[2],vr0[3] }, a1_ = { vr0[4],vr0[5],vr0[6],vr0[7] }; \
        bf16x4 b0_ = { vr1[0],vr1[1],vr1[2],vr1[3] }, b1_ = { vr1[4],vr1[5],vr1[6],vr1[7] }; \
        bf16x4 c0_ = { vr2[0],vr2[1],vr2[2],vr2[3] }, c1_ = { vr2[4],vr2[5],vr2[6],vr2[7] }; \
        bf16x4 d0_ = { vr3[0],vr3[1],vr3[2],vr3[3] }, d1_ = { vr3[4],vr3[5],vr3[6],vr3[7] }; \
        *(bf16x4*)&nV[krow * 72 + kc16]            = a0_;                             \
        *(bf16x4*)&nV[krow * 72 + kc16 + 8]        = a1_;                             \
        *(bf16x4*)&nV[krow * 72 + kc16 + 4]        = b0_;                             \
        *(bf16x4*)&nV[krow * 72 + kc16 + 12]       = b1_;                             \
        *(bf16x4*)&nV[(32 + krow) * 72 + kc16]     = c0_;                             \
        *(bf16x4*)&nV[(32 + krow) * 72 + kc16 + 8] = c1_;                             \
        *(bf16x4*)&nV[(32 + krow) * 72 + kc16 + 4] = d0_;                             \
        *(bf16x4*)&nV[(32 + krow) * 72 + kc16 + 12]= d1_;                             \
    } while (0)

    fx16 ovA0, ovA1, ovB0, ovB1;
#pragma unroll
    for (int i = 0; i < 16; ++i) { ovA0[i] = 0.f; ovA1[i] = 0.f; ovB0[i] = 0.f; ovB1[i] = 0.f; }
    float l_accA = 0.f, l_accB = 0.f;

    LOADREGS(grp);            // tile 0 of this group
    STAGE(0);
    LOADREGS(2 + grp);        // tile 1
    asm volatile("s_waitcnt lgkmcnt(0)" ::: "memory");
    __builtin_amdgcn_s_barrier();
    __builtin_amdgcn_sched_barrier(0);

#define PVQ(KCV, SCA, SCB, C) do {                                                    \
        const bf16x8 va0 = *(const bf16x8*)&lVg[l32 * 72 + (KCV) * 16 + hi * 8];      \
        const bf16x8 va1 = *(const bf16x8*)&lVg[(32 + l32) * 72 + (KCV) * 16 + hi * 8]; \
        bf16x8 pbA, pbB; float psA[8], psB[8];                                        \
        _Pragma("unroll")                                                             \
        for (int j = 0; j < 8; ++j) {                                                 \
            psA[j] = __builtin_amdgcn_exp2f((SCA)[(C) * 8 + j]); pbA[j] = (__bf16)psA[j]; \
            psB[j] = __builtin_amdgcn_exp2f((SCB)[(C) * 8 + j]); pbB[j] = (__bf16)psB[j]; \
        }                                                                             \
        l_accA += ((psA[0]+psA[1]) + (psA[2]+psA[3])) + ((psA[4]+psA[5]) + (psA[6]+psA[7])); \
        l_accB += ((psB[0]+psB[1]) + (psB[2]+psB[3])) + ((psB[4]+psB[5]) + (psB[6]+psB[7])); \
        __builtin_amdgcn_s_setprio(1);                                                \
        ovA0 = __builtin_amdgcn_mfma_f32_32x32x16_bf16(va0, pbA, ovA0, 0, 0, 0);      \
        ovA1 = __builtin_amdgcn_mfma_f32_32x32x16_bf16(va1, pbA, ovA1, 0, 0, 0);      \
        ovB0 = __builtin_amdgcn_mfma_f32_32x32x16_bf16(va0, pbB, ovB0, 0, 0, 0);      \
        ovB1 = __builtin_amdgcn_mfma_f32_32x32x16_bf16(va1, pbB, ovB1, 0, 0, 0);      \
        __builtin_amdgcn_s_setprio(0);                                                \
    } while (0)

    for (int it = 0; it < 16; ++it) {
        const __bf16* lKg = &smem[it & 1][goff];
        const __bf16* lVg = lKg + 4608;

        if (it + 1 < 16) {
            STAGE((it + 1) & 1);
            const int it2 = (it + 2 < 16) ? it + 2 : 15;   // clamped (redundant reload ok)
            LOADREGS(it2 * 2 + grp);
        }

        // S^T = K . Q^T for both 32-row Q sub-blocks (K fragments a0/a1 shared)
        fx16 sc0, sc1, sc2, sc3;
#pragma unroll
        for (int i = 0; i < 16; ++i) { sc0[i] = 0.f; sc1[i] = 0.f; sc2[i] = 0.f; sc3[i] = 0.f; }
        __builtin_amdgcn_s_setprio(1);
#pragma unroll
        for (int kc = 0; kc < 4; ++kc) {
            const bf16x8 a0 = *(const bf16x8*)&lKg[l32 * 72 + kc * 16 + hi * 8];
            const bf16x8 a1 = *(const bf16x8*)&lKg[(32 + l32) * 72 + kc * 16 + hi * 8];
            sc0 = __builtin_amdgcn_mfma_f32_32x32x16_bf16(a0, qfA[kc], sc0, 0, 0, 0);
            sc1 = __builtin_amdgcn_mfma_f32_32x32x16_bf16(a1, qfA[kc], sc1, 0, 0, 0);
            sc2 = __builtin_amdgcn_mfma_f32_32x32x16_bf16(a0, qfB[kc], sc2, 0, 0, 0);
            sc3 = __builtin_amdgcn_mfma_f32_32x32x16_bf16(a1, qfB[kc], sc3, 0, 0, 0);
        }
        __builtin_amdgcn_s_setprio(0);

        // fixed-max softmax fused into PV; V fragments va0/va1 shared by both sub-blocks
        PVQ(0, sc0, sc2, 0);
        PVQ(1, sc0, sc2, 1);
        PVQ(2, sc1, sc3, 0);
        PVQ(3, sc1, sc3, 1);

        asm volatile("s_waitcnt lgkmcnt(0)" ::: "memory");
        __builtin_amdgcn_s_barrier();
        __builtin_amdgcn_sched_barrier(0);
    }

    const float lpA = l_accA + __shfl_xor(l_accA, 32, 64);
    const float lpB = l_accB + __shfl_xor(l_accB, 32, 64);

    // cross-group combine, overlaid on smem (32768 B of fx4 chunks + 512 B of l at byte 32768)
    fx4* lO = (fx4*)&smem[0][0];
    float* lL = (float*)((char*)&smem[0][0] + 32768);
    if (grp == 1) {
#pragma unroll
        for (int ic = 0; ic < 4; ++ic) {
            fx4 cA0, cA1, cB0, cB1;
#pragma unroll
            for (int r = 0; r < 4; ++r) {
                cA0[r] = ovA0[ic * 4 + r]; cA1[r] = ovA1[ic * 4 + r];
                cB0[r] = ovB0[ic * 4 + r]; cB1[r] = ovB1[ic * 4 + r];
            }
            lO[((w2 * 2 + 0) * 8 + ic    ) * 64 + lane] = cA0;
            lO[((w2 * 2 + 0) * 8 + ic + 4) * 64 + lane] = cA1;
            lO[((w2 * 2 + 1) * 8 + ic    ) * 64 + lane] = cB0;
            lO[((w2 * 2 + 1) * 8 + ic + 4) * 64 + lane] = cB1;
        }
        if (hi == 0) { lL[(w2 * 2 + 0) * 32 + l32] = lpA; lL[(w2 * 2 + 1) * 32 + l32] = lpB; }
    }
    __syncthreads();
    if (grp == 0) {
#pragma unroll
        for (int ic = 0; ic < 4; ++ic) {
            const fx4 cA0 = lO[((w2 * 2 + 0) * 8 + ic    ) * 64 + lane];
            const fx4 cA1 = lO[((w2 * 2 + 0) * 8 + ic + 4) * 64 + lane];
            const fx4 cB0 = lO[((w2 * 2 + 1) * 8 + ic    ) * 64 + lane];
            const fx4 cB1 = lO[((w2 * 2 + 1) * 8 + ic + 4) * 64 + lane];
#pragma unroll
            for (int r = 0; r < 4; ++r) {
                ovA0[ic * 4 + r] += cA0[r]; ovA1[ic * 4 + r] += cA1[r];
                ovB0[ic * 4 + r] += cB0[r]; ovB1[ic * 4 + r] += cB1[r];
            }
        }
        const float invA = 1.0f / (lpA + lL[(w2 * 2 + 0) * 32 + l32]);
        const float invB = 1.0f / (lpB + lL[(w2 * 2 + 1) * 32 + l32]);
#pragma unroll
        for (int dt = 0; dt < 2; ++dt)
#pragma unroll
            for (int rg2 = 0; rg2 < 4; ++rg2) {
                bf16x4 oA, oB;
#pragma unroll
                for (int r = 0; r < 4; ++r) {
                    oA[r] = (__bf16)((dt ? ovA1[rg2 * 4 + r] : ovA0[rg2 * 4 + r]) * invA);
                    oB[r] = (__bf16)((dt ? ovB1[rg2 * 4 + r] : ovB0[rg2 * 4 + r]) * invB);
                }
                const int col = h * 64 + dt * 32 + rg2 * 8 + hi * 4;
                *(bf16x4*)(O + (size_t)qrowA * 2048 + col) = oA;
                *(bf16x4*)(O + (size_t)(qrowA + 32) * 2048 + col) = oB;
            }
    }
#undef LOADREGS
#undef STAGE
#undef PVQ
}

// ----------------------------------------------------------------------------
extern "C" void kernel_launch(void* const* d_in, const int* in_sizes, int n_in,
                              void* d_out, int out_size, void* d_ws, size_t ws_size,
                              hipStream_t stream) {
    const float* x  = (const float*)d_in[0];
    const float* wq = (const float*)d_in[1];
    const float* wk = (const float*)d_in[2];
    const float* wv = (const float*)d_in[3];
    const float* wo = (const float*)d_in[4];
    float* out = (float*)d_out;
    char* ws = (char*)d_ws;

    __bf16* Xb    = (__bf16*)ws;                        // [0, 8M)
    __bf16* WqkvT = (__bf16*)(ws + ((size_t)8 << 20));  // [8M, 20M)  3072 x 2048
    __bf16* WoT   = (__bf16*)(ws + ((size_t)20 << 20)); // [20M, 28M) 2048 x 2048
    __bf16* Qr    = (__bf16*)(ws + ((size_t)28 << 20)); // [28M, 36M) 32 x 2048 x 64
    __bf16* Kr    = (__bf16*)(ws + ((size_t)36 << 20)); // [36M, 38M)  8 x 2048 x 64
    __bf16* Vt    = (__bf16*)(ws + ((size_t)38 << 20)); // [38M, 40M)  8 x 64 x 2048
    __bf16* Ob    = (__bf16*)(ws + ((size_t)40 << 20)); // [40M, 48M) 2048 x 2048
    float*  Cp    = (float*)ws;                         // [0, 16.8M) split-K partial (Xb/WqkvT dead)

    prep<<<4096 + 5120, 256, 0, stream>>>((const float4*)x, Xb, wq, wk, wv, wo, WqkvT, WoT);
    gemm_qkv<<<384, 256, 0, stream>>>(Xb, WqkvT, Qr, Kr, Vt);
    flash_attn<<<dim3(16, 32), 256, 0, stream>>>(Qr, Kr, Vt, Ob);
    gemm_out_sk<<<512, 256, 0, stream>>>(Ob, WoT, out, Cp);
    reduce_add<<<4096, 256, 0, stream>>>((float4*)out, (const float4*)Cp);
}